// Round 2
// baseline (179.951 us; speedup 1.0000x reference)
//
#include <hip/hip_runtime.h>
#include <hip/hip_bf16.h>

#define CIN   256
#define COUT  32
#define IMG_H 96
#define IMG_W 96
#define HW    (IMG_H*IMG_W)
#define NB    2
#define NV    4
#define VSZ   64
#define NVOX  (VSZ*VSZ*VSZ)

typedef __attribute__((ext_vector_type(2))) float f32x2;

__device__ __forceinline__ float fast_exp2(float x) {
    float r;
    asm("v_exp_f32 %0, %1" : "=v"(r) : "v"(x));
    return r;
}

// Kernel 1: 1x1 conv -> channel-last bf16 [b,v,h,w,c].  (unchanged this round
// for attribution; will be A/B'd next round)
__global__ __launch_bounds__(256) void conv1x1_kernel(
    const float* __restrict__ features,   // [B,V,CIN,H,W] fp32
    const float* __restrict__ Wp,         // [COUT,CIN]
    const float* __restrict__ bp,         // [COUT]
    __hip_bfloat16* __restrict__ out)     // [B,V,H,W,COUT] bf16
{
    const int og   = __builtin_amdgcn_readfirstlane((threadIdx.x >> 6) & 3);
    const int lane = threadIdx.x & 63;
    const int bv   = blockIdx.y;
    const int px   = blockIdx.x*64 + lane;
    const float* f     = features + (size_t)bv*CIN*HW + px;
    const float* wbase = Wp + (size_t)og*8*CIN;     // uniform -> scalar base

    float acc[8];
    #pragma unroll
    for (int j = 0; j < 8; ++j) acc[j] = bp[og*8 + j];   // uniform -> s_load

    for (int cc = 0; cc < CIN; cc += 8) {
        float x[8];
        #pragma unroll
        for (int i = 0; i < 8; ++i)                  // 8 indep coalesced loads
            x[i] = f[(size_t)(cc + i)*HW];
        #pragma unroll
        for (int i = 0; i < 8; ++i) {
            #pragma unroll
            for (int j = 0; j < 8; ++j)              // v_fmac v, s, v
                acc[j] += x[i] * wbase[(size_t)j*CIN + cc + i];
        }
    }

    union { uint4 u4; __hip_bfloat16 h[8]; } pk;
    #pragma unroll
    for (int j = 0; j < 8; ++j) pk.h[j] = __float2bfloat16(acc[j]);
    *(uint4*)(out + ((size_t)(bv*HW + px))*COUT + og*8) = pk.u4;
}

// Kernel 2 (R6): voxel-per-lane, software-pipelined gathers.
// R5 post-mortem: volgen ~43us vs ~17us issue-floor -> load-latency bound
// (only 4 gathers in flight, consumed immediately) + possible occupancy
// drop past 64 VGPR. This version:
//  - prefetches view v+1's 4 corner lines while processing view v
//  - __launch_bounds__(256,4) pins VGPR<=128 -> 4 waves/SIMD guaranteed
//  - log2(e) folded into bilinear weights: exp is a bare v_exp_f32,
//    final result scaled by ln2 (B' = log2e*B cancels in B/A up to ln2)
//  - first-corner mul (no zero-init of s2), first-view set of A2/B2
//  - off[] stored as BYTE offsets; ch0*2 folds into the load's imm offset
__global__ __launch_bounds__(256, 4) void volgen_kernel(
    const __hip_bfloat16* __restrict__ feats,  // [B,V,H,W,COUT] bf16
    const float* __restrict__ proj,            // [B,V,3,4]
    const float* __restrict__ coords,          // [B,NVOX,3]
    float* __restrict__ out)                   // [B,COUT,NVOX]
{
    const int tid = threadIdx.x;
    const int b   = blockIdx.y;
    const int n   = blockIdx.x*256 + tid;

    const float* cp = coords + ((size_t)b*NVOX + n)*3;
    const float X = cp[0], Y = cp[1], Z = cp[2];

    const float LOG2E = 1.4426950408889634f;

    int   off[NV][4];                          // byte offsets into feats
    float wgt[NV][4];                          // bilinear weight * log2(e)
    #pragma unroll
    for (int v = 0; v < NV; ++v) {
        const float* P = proj + (size_t)(b*NV + v)*12;   // uniform -> scalar
        const float wz = P[8]*X + P[9]*Y + P[10]*Z + P[11];
        const bool  vz = wz > 0.f;
        const float rz = __builtin_amdgcn_rcpf(wz);
        float px = (P[0]*X + P[1]*Y + P[2]*Z + P[3]) * rz * (95.f/96.f);
        float py = (P[4]*X + P[5]*Y + P[6]*Z + P[7]) * rz * (95.f/96.f);
        px = vz ? px : 0.f;  py = vz ? py : 0.f;
        px = fminf(fmaxf(px, -1.0e6f), 1.0e6f);
        py = fminf(fmaxf(py, -1.0e6f), 1.0e6f);
        const float fx0 = floorf(px), fy0 = floorf(py);
        const int x0 = (int)fx0, y0 = (int)fy0, x1 = x0+1, y1 = y0+1;
        const float wx1 = px - fx0, wx0 = 1.f - wx1;
        const float wy1 = py - fy0, wy0 = 1.f - wy1;
        const bool vx0 = (unsigned)x0 < (unsigned)IMG_W;
        const bool vx1 = (unsigned)x1 < (unsigned)IMG_W;
        const bool vy0 = (unsigned)y0 < (unsigned)IMG_H;
        const bool vy1 = (unsigned)y1 < (unsigned)IMG_H;
        const int cx0 = min(max(x0, 0), IMG_W-1), cx1 = min(max(x1, 0), IMG_W-1);
        const int cy0 = min(max(y0, 0), IMG_H-1), cy1 = min(max(y1, 0), IMG_H-1);
        const int base = ((b*NV + v)*HW)*COUT*2;         // bytes, uniform
        off[v][0] = base + (cy0*IMG_W + cx0)*(COUT*2);  wgt[v][0] = (vz & vx0 & vy0) ? wx0*wy0*LOG2E : 0.f;
        off[v][1] = base + (cy0*IMG_W + cx1)*(COUT*2);  wgt[v][1] = (vz & vx1 & vy0) ? wx1*wy0*LOG2E : 0.f;
        off[v][2] = base + (cy1*IMG_W + cx0)*(COUT*2);  wgt[v][2] = (vz & vx0 & vy1) ? wx0*wy1*LOG2E : 0.f;
        off[v][3] = base + (cy1*IMG_W + cx1)*(COUT*2);  wgt[v][3] = (vz & vx1 & vy1) ? wx1*wy1*LOG2E : 0.f;
    }

    const char* fb = (const char*)feats;
    const size_t ob = (size_t)b*COUT*NVOX + n;
    const float LN2 = 0.6931471805599453f;

    for (int ch0 = 0; ch0 < COUT; ch0 += 8) {
        f32x2 A2[4], B2[4];
        uint4 t[4], tn[4];

        #pragma unroll
        for (int c = 0; c < 4; ++c)                     // prime the pipeline
            t[c] = *(const uint4*)(fb + off[0][c] + ch0*2);

        #pragma unroll
        for (int v = 0; v < NV; ++v) {
            if (v < NV-1) {
                #pragma unroll
                for (int c = 0; c < 4; ++c)             // prefetch next view
                    tn[c] = *(const uint4*)(fb + off[v+1][c] + ch0*2);
            }

            f32x2 s2[4];
            #pragma unroll
            for (int c = 0; c < 4; ++c) {
                const float w = wgt[v][c];
                const f32x2 w2 = { w, w };
                const unsigned tu[4] = { t[c].x, t[c].y, t[c].z, t[c].w };
                #pragma unroll
                for (int k = 0; k < 4; ++k) {           // packed fma: 2 ch/instr
                    f32x2 f2;
                    f2.x = __uint_as_float(tu[k] << 16);
                    f2.y = __uint_as_float(tu[k] & 0xffff0000u);
                    if (c == 0) s2[k] = w2 * f2;        // no zero-init
                    else        s2[k] += w2 * f2;
                }
            }

            #pragma unroll
            for (int k = 0; k < 4; ++k) {
                f32x2 e2;
                e2.x = fast_exp2(s2[k].x);              // wgt pre-scaled: 2^s' = e^s
                e2.y = fast_exp2(s2[k].y);
                if (v == 0) { A2[k] = e2;  B2[k] = s2[k]*e2; }
                else        { A2[k] += e2; B2[k] += s2[k]*e2; }
            }

            if (v < NV-1) {
                #pragma unroll
                for (int c = 0; c < 4; ++c) t[c] = tn[c];   // rotate
            }
        }

        #pragma unroll
        for (int k = 0; k < 4; ++k) {                   // coalesced stores
            out[ob + (size_t)(ch0 + 2*k    )*NVOX] = B2[k].x * __builtin_amdgcn_rcpf(A2[k].x) * LN2;
            out[ob + (size_t)(ch0 + 2*k + 1)*NVOX] = B2[k].y * __builtin_amdgcn_rcpf(A2[k].y) * LN2;
        }
    }
}

extern "C" void kernel_launch(void* const* d_in, const int* in_sizes, int n_in,
                              void* d_out, int out_size, void* d_ws, size_t ws_size,
                              hipStream_t stream)
{
    const float* features = (const float*)d_in[0];   // [2,4,256,96,96]
    const float* proj     = (const float*)d_in[1];   // [2,4,3,4]
    const float* coords   = (const float*)d_in[2];   // [2,64,64,64,3]
    const float* Wp       = (const float*)d_in[3];   // [32,256]
    const float* bp       = (const float*)d_in[4];   // [32]
    float* out = (float*)d_out;                      // [2,32,64,64,64]
    __hip_bfloat16* featsT = (__hip_bfloat16*)d_ws;  // [2,4,96,96,32] bf16 = 4.72 MB

    hipLaunchKernelGGL(conv1x1_kernel, dim3(HW/64, NB*NV), dim3(256), 0, stream,
                       features, Wp, bp, featsT);
    hipLaunchKernelGGL(volgen_kernel, dim3(NVOX/256, NB), dim3(256), 0, stream,
                       featsT, proj, coords, out);
}